// Round 3
// baseline (590.208 us; speedup 1.0000x reference)
//
#include <hip/hip_runtime.h>
#include <hip/hip_bf16.h>
#include <math.h>

#define BATCH 65536
#define DIM 256
#define KC 1024
#define COMMIT 0.25f
#define DECAY 0.99f
#define EPSV 1e-5f

// Output layout (floats, concatenated in reference return order)
#define O_ZQ   0                       // 65536*256
#define O_LOSS 16777216                // 1
#define O_PERP 16777217                // 1
#define O_IDX  16777218                // 65536 (indices written as float values)
#define O_EMB  16842754                // 1024*256 new_embedding
#define O_NCS  17104898                // 1024 new_ema_cluster_size
#define O_NEW  17105922                // 1024*256 new_ema_w

typedef __attribute__((ext_vector_type(8))) short bf16x8;
typedef __attribute__((ext_vector_type(4))) float f32x4;

typedef __attribute__((address_space(1))) const void* as1_cvp;
typedef __attribute__((address_space(3))) void* as3_vp;

__device__ __forceinline__ void gload_lds16(const void* g, void* l) {
    // async 16B global->LDS (DMA path); LDS dest = wave-uniform base + lane*16
    __builtin_amdgcn_global_load_lds((as1_cvp)g, (as3_vp)l, 16, 0, 0);
}

__device__ __forceinline__ unsigned short bf16_rne(float x) {
    unsigned u = __builtin_bit_cast(unsigned, x);
    unsigned r = (u + 0x7FFFu + ((u >> 16) & 1u)) >> 16;
    return (unsigned short)r;
}
__device__ __forceinline__ float bf16_to_f(unsigned short h) {
    unsigned u = ((unsigned)h) << 16;
    return __builtin_bit_cast(float, u);
}

// ---------------- fused: zero accumulators + emb hi/lo split + e_sq ---------
// 1024 blocks x 256 thr. Block k: zeroes dw row k, prepares code row k
// (threads 0..63), zeroes counts[k] (thread 64), block 0 zeroes O_LOSS.
// Global layout per code row k (256 ushorts = 32 slots of 8): ORIGINAL slot s
// stored at slot (s ^ (k&7)).  Staging copies rows linearly into LDS via
// global_load_lds; the MFMA fragment read applies the same XOR -> identity,
// and the XOR spreads a wave's 16 rows across bank groups without padding.
__global__ __launch_bounds__(256) void prep_zero_kernel(
        const float* __restrict__ emb,
        unsigned short* __restrict__ ehi, unsigned short* __restrict__ elo,
        float* __restrict__ e_sq, float* __restrict__ dw,
        int* __restrict__ counts, float* __restrict__ out) {
    int k = blockIdx.x;
    int t = threadIdx.x;
    dw[(size_t)k * DIM + t] = 0.0f;
    if (t == 64) counts[k] = 0;
    if (k == 0 && t == 128) out[O_LOSS] = 0.0f;
    if (t < 64) {
        int lane = t;
        const float4* ep = (const float4*)(emb + (size_t)k * DIM);
        float4 e = ep[lane];
        float x[4] = {e.x, e.y, e.z, e.w};
        unsigned h[4], l[4];
        float s = 0.0f;
        #pragma unroll
        for (int j = 0; j < 4; ++j) {
            h[j] = bf16_rne(x[j]);
            l[j] = bf16_rne(x[j] - bf16_to_f((unsigned short)h[j]));
            s += x[j] * x[j];
        }
        uint2 ph = make_uint2(h[0] | (h[1] << 16), h[2] | (h[3] << 16));
        uint2 pl = make_uint2(l[0] | (l[1] << 16), l[2] | (l[3] << 16));
        int slot = lane >> 1;            // 16B slot (8 ushorts)
        int half = lane & 1;             // which 8B half of the slot
        int us = k * 256 + ((slot ^ (k & 7)) << 3) + (half << 2);
        *(uint2*)(ehi + us) = ph;
        *(uint2*)(elo + us) = pl;
        for (int off = 32; off; off >>= 1) s += __shfl_down(s, off, 64);
        if (lane == 0) e_sq[k] = s;
    }
}

// ---------------- MFMA distance + argmin (+fused histogram) -----------------
// CH_ROWS=16: 2x(8+8) KB double buffer + 4 KB esq = 36 KB LDS -> 4 blocks/CU
// (16 waves/CU, up from 8).  Same 2-phase schedule; numerics identical to
// the 32-row version (same MFMA order, same tie-break).
#define CH_ROWS 16
__global__ __launch_bounds__(256, 4) void argmin_kernel(
        const float* __restrict__ z_e,
        const unsigned short* __restrict__ ehi,
        const unsigned short* __restrict__ elo,
        const float* __restrict__ e_sq,
        int* __restrict__ idx_out, float* __restrict__ idx_f_out,
        int* __restrict__ counts) {
    __shared__ __align__(16) unsigned short bhi_s[2][CH_ROWS * 256]; // 2x8 KB
    __shared__ __align__(16) unsigned short blo_s[2][CH_ROWS * 256]; // 2x8 KB
    __shared__ float esq_s[KC];

    int tid = threadIdx.x;
    int w = tid >> 6;
    int lane = tid & 63;
    int m16 = lane & 15;
    int quad = lane >> 4;
    int base_m = blockIdx.x * 128 + w * 32;

#define STAGE(c, b) { \
    const char* gh_ = (const char*)ehi + (c) * 8192 + tid * 16; \
    const char* gl_ = (const char*)elo + (c) * 8192 + tid * 16; \
    char* lh_ = (char*)(bhi_s[b]) + tid * 16; \
    char* ll_ = (char*)(blo_s[b]) + tid * 16; \
    _Pragma("unroll") for (int r_ = 0; r_ < 2; ++r_) { \
        gload_lds16(gh_ + r_ * 4096, lh_ + r_ * 4096); \
        gload_lds16(gl_ + r_ * 4096, ll_ + r_ * 4096); } }

    // issue chunk-0 DMA first; A-fragment conversion below overlaps it
    STAGE(0, 0)

    #pragma unroll
    for (int i = 0; i < 4; ++i) esq_s[tid + i * 256] = e_sq[tid + i * 256];

    // load + split A fragments: A[m=lane&15][k=quad*8+j]
    bf16x8 ahi[2][8], alo[2][8];
    #pragma unroll
    for (int f = 0; f < 2; ++f) {
        const float* zr = z_e + (size_t)(base_m + f * 16 + m16) * DIM;
        #pragma unroll
        for (int ks = 0; ks < 8; ++ks) {
            const float4* p = (const float4*)(zr + ks * 32 + quad * 8);
            float4 x0 = p[0], x1 = p[1];
            float xs[8] = {x0.x, x0.y, x0.z, x0.w, x1.x, x1.y, x1.z, x1.w};
            #pragma unroll
            for (int j = 0; j < 8; ++j) {
                unsigned short h = bf16_rne(xs[j]);
                unsigned short l = bf16_rne(xs[j] - bf16_to_f(h));
                ahi[f][ks][j] = (short)h;
                alo[f][ks][j] = (short)l;
            }
        }
    }

    float best0[4] = {1e30f, 1e30f, 1e30f, 1e30f};
    float best1[4] = {1e30f, 1e30f, 1e30f, 1e30f};
    int bk0[4] = {0, 0, 0, 0};
    int bk1[4] = {0, 0, 0, 0};

    const int rsw = (m16 & 7) << 3;   // read-side XOR (in ushort units)

#define COMPUTE(c, b) { \
    f32x4 acc0 = {0.f, 0.f, 0.f, 0.f}; \
    f32x4 acc1 = {0.f, 0.f, 0.f, 0.f}; \
    const unsigned short* bh_row = bhi_s[b] + m16 * 256; \
    const unsigned short* bl_row = blo_s[b] + m16 * 256; \
    _Pragma("unroll") for (int ks_ = 0; ks_ < 8; ++ks_) { \
        int us_off = (((ks_ * 4 + quad) << 3) ^ rsw); \
        bf16x8 bh = *(const bf16x8*)(bh_row + us_off); \
        bf16x8 bl = *(const bf16x8*)(bl_row + us_off); \
        acc0 = __builtin_amdgcn_mfma_f32_16x16x32_bf16(ahi[0][ks_], bh, acc0, 0, 0, 0); \
        acc1 = __builtin_amdgcn_mfma_f32_16x16x32_bf16(ahi[1][ks_], bh, acc1, 0, 0, 0); \
        acc0 = __builtin_amdgcn_mfma_f32_16x16x32_bf16(ahi[0][ks_], bl, acc0, 0, 0, 0); \
        acc1 = __builtin_amdgcn_mfma_f32_16x16x32_bf16(ahi[1][ks_], bl, acc1, 0, 0, 0); \
        acc0 = __builtin_amdgcn_mfma_f32_16x16x32_bf16(alo[0][ks_], bh, acc0, 0, 0, 0); \
        acc1 = __builtin_amdgcn_mfma_f32_16x16x32_bf16(alo[1][ks_], bh, acc1, 0, 0, 0); } \
    int col = (c) * 16 + m16; \
    float es = esq_s[col]; \
    _Pragma("unroll") for (int r_ = 0; r_ < 4; ++r_) { \
        float d0 = es - 2.0f * acc0[r_]; \
        float d1 = es - 2.0f * acc1[r_]; \
        if (d0 < best0[r_]) { best0[r_] = d0; bk0[r_] = col; } \
        if (d1 < best1[r_]) { best1[r_] = d1; bk1[r_] = col; } } }

    __syncthreads();   // chunk-0 DMA + esq_s visible

    for (int c = 0; c < 64; c += 2) {
        STAGE(c + 1, 1)
        COMPUTE(c, 0)
        __syncthreads();           // drains STAGE(c+1); buf0 reads finished
        if (c + 2 < 64) STAGE(c + 2, 0)
        COMPUTE(c + 1, 1)
        __syncthreads();           // drains STAGE(c+2); buf1 reads finished
    }

    #pragma unroll
    for (int off = 1; off < 16; off <<= 1) {
        #pragma unroll
        for (int r = 0; r < 4; ++r) {
            float ov0 = __shfl_xor(best0[r], off, 64);
            int   ok0 = __shfl_xor(bk0[r], off, 64);
            if (ov0 < best0[r] || (ov0 == best0[r] && ok0 < bk0[r])) { best0[r] = ov0; bk0[r] = ok0; }
            float ov1 = __shfl_xor(best1[r], off, 64);
            int   ok1 = __shfl_xor(bk1[r], off, 64);
            if (ov1 < best1[r] || (ov1 == best1[r] && ok1 < bk1[r])) { best1[r] = ov1; bk1[r] = ok1; }
        }
    }
    if (m16 == 0) {
        #pragma unroll
        for (int r = 0; r < 4; ++r) {
            int row0 = base_m + quad * 4 + r;
            int row1 = base_m + 16 + quad * 4 + r;
            idx_out[row0] = bk0[r];
            idx_f_out[row0] = (float)bk0[r];
            idx_out[row1] = bk1[r];
            idx_f_out[row1] = (float)bk1[r];
            atomicAdd(&counts[bk0[r]], 1);   // fused histogram
            atomicAdd(&counts[bk1[r]], 1);
        }
    }
#undef STAGE
#undef COMPUTE
}

// ---------------- prefix scan + cluster stats (ncs, n, perplexity) ----------
__global__ __launch_bounds__(1024) void prefix_stats_kernel(
        const int* __restrict__ counts, int* __restrict__ cursor,
        const float* __restrict__ ema_cs, float* __restrict__ out,
        float* __restrict__ n_ws) {
    __shared__ int wsum[16];
    __shared__ float s1[1024];
    __shared__ float s2[1024];
    int t = threadIdx.x;
    int lane = t & 63;
    int wv = t >> 6;
    int c = counts[t];
    int x = c;
    #pragma unroll
    for (int off = 1; off < 64; off <<= 1) {
        int v = __shfl_up(x, off, 64);
        if (lane >= off) x += v;
    }
    if (lane == 63) wsum[wv] = x;
    // cluster stats while the scan syncs
    float cf = (float)c;
    float ncs = DECAY * ema_cs[t] + (1.0f - DECAY) * cf;
    out[O_NCS + t] = ncs;
    float p = cf / (float)BATCH;
    s1[t] = ncs;
    s2[t] = p * logf(p + 1e-10f);
    __syncthreads();
    if (wv == 0) {
        int v = (lane < 16) ? wsum[lane] : 0;
        #pragma unroll
        for (int off = 1; off < 16; off <<= 1) {
            int u = __shfl_up(v, off, 64);
            if (lane >= off) v += u;
        }
        if (lane < 16) wsum[lane] = v;
    }
    __syncthreads();
    int woff = (wv == 0) ? 0 : wsum[wv - 1];
    cursor[t] = woff + x - c;   // exclusive
    for (int s = 512; s; s >>= 1) {
        if (t < s) { s1[t] += s1[t + s]; s2[t] += s2[t + s]; }
        __syncthreads();
    }
    if (t == 0) {
        n_ws[0] = s1[0];
        out[O_PERP] = expf(-s2[0]);
    }
}

// ---------------- bucket rows by cluster ------------------------------------
__global__ __launch_bounds__(256) void scatter_rows_kernel(
        const int* __restrict__ idx, int* __restrict__ cursor,
        int* __restrict__ sorted_rows) {
    int i = blockIdx.x * 256 + threadIdx.x;
    int k = idx[i];
    int pos = atomicAdd(&cursor[k], 1);
    sorted_rows[pos] = i;
}

// ---------------- fused: z_q gather + loss + dw ------------------------------
// 4 waves/block; wave w owns rows [w*16, w*16+16) of the block's 64-row
// segment; lane owns a float4 column slice (16 B/lane coalescing).  Loads
// batched 8-deep; per-key running float4 acc flushed via atomics on change.
// Loss partial is pre-scaled and atomically added straight to out[O_LOSS].
#define SEG 64
__global__ __launch_bounds__(256) void dw_zq_kernel(
        const float* __restrict__ z_e, const float* __restrict__ emb,
        const int* __restrict__ idx, const int* __restrict__ sorted_rows,
        float* __restrict__ zq_out, float* __restrict__ dw,
        float* __restrict__ out) {
    __shared__ int rows_s[SEG];
    __shared__ int keys_s[SEG];
    int t = threadIdx.x;
    int w = t >> 6;
    int lane = t & 63;
    int base = blockIdx.x * SEG;
    if (t < SEG) {
        int r = sorted_rows[base + t];
        rows_s[t] = r;
        keys_s[t] = idx[r];
    }
    __syncthreads();

    int c4 = lane * 4;
    float4 acc = make_float4(0.f, 0.f, 0.f, 0.f);
    float lsum = 0.0f;
    int kprev = keys_s[w * 16];
    #pragma unroll
    for (int g = 0; g < 2; ++g) {
        int rowb[8], kb[8];
        float4 zb[8], qb[8];
        #pragma unroll
        for (int u = 0; u < 8; ++u) {
            int i = w * 16 + g * 8 + u;
            rowb[u] = rows_s[i];
            kb[u] = keys_s[i];
        }
        #pragma unroll
        for (int u = 0; u < 8; ++u) {
            zb[u] = *(const float4*)(z_e + (size_t)rowb[u] * DIM + c4);
            qb[u] = *(const float4*)(emb + (size_t)kb[u] * DIM + c4);
        }
        #pragma unroll
        for (int u = 0; u < 8; ++u) {
            float4 z = zb[u], q = qb[u];
            float4 d = make_float4(q.x - z.x, q.y - z.y, q.z - z.z, q.w - z.w);
            float4 o = make_float4(z.x + d.x, z.y + d.y, z.z + d.z, z.w + d.w);
            *(float4*)(zq_out + (size_t)rowb[u] * DIM + c4) = o;
            lsum += d.x * d.x + d.y * d.y + d.z * d.z + d.w * d.w;
            if (kb[u] != kprev) {
                float* dst = dw + (size_t)kprev * DIM + c4;
                atomicAdd(dst + 0, acc.x);
                atomicAdd(dst + 1, acc.y);
                atomicAdd(dst + 2, acc.z);
                atomicAdd(dst + 3, acc.w);
                acc = make_float4(0.f, 0.f, 0.f, 0.f);
                kprev = kb[u];
            }
            acc.x += z.x; acc.y += z.y; acc.z += z.z; acc.w += z.w;
        }
    }
    {
        float* dst = dw + (size_t)kprev * DIM + c4;
        atomicAdd(dst + 0, acc.x);
        atomicAdd(dst + 1, acc.y);
        atomicAdd(dst + 2, acc.z);
        atomicAdd(dst + 3, acc.w);
    }

    __shared__ float red[256];
    red[t] = lsum;
    __syncthreads();
    for (int s = 128; s; s >>= 1) {
        if (t < s) red[t] += red[t + s];
        __syncthreads();
    }
    if (t == 0)
        atomicAdd(out + O_LOSS, red[0] * (COMMIT / ((float)BATCH * (float)DIM)));
}

// ---------------- new_ema_w and new_embedding -------------------------------
__global__ __launch_bounds__(256) void finalize_emb(
        const float* __restrict__ ema_w, const float* __restrict__ dw,
        const float* __restrict__ ncs_arr, const float* __restrict__ n_ws,
        float* __restrict__ out_emb, float* __restrict__ out_emaw) {
    int k = blockIdx.x;
    int d = threadIdx.x;
    size_t i = (size_t)k * DIM + d;
    float w = DECAY * ema_w[i] + (1.0f - DECAY) * dw[i];
    out_emaw[i] = w;
    float n = n_ws[0];
    float ncs = ncs_arr[k];
    float smoothed = (ncs + EPSV) / (n + (float)KC * EPSV) * n;
    out_emb[i] = w / smoothed;
}

extern "C" void kernel_launch(void* const* d_in, const int* in_sizes, int n_in,
                              void* d_out, int out_size, void* d_ws, size_t ws_size,
                              hipStream_t stream) {
    const float* z_e    = (const float*)d_in[0];
    const float* emb    = (const float*)d_in[1];
    const float* ema_cs = (const float*)d_in[2];
    const float* ema_w  = (const float*)d_in[3];
    float* out = (float*)d_out;
    float* ws = (float*)d_ws;

    // workspace layout (16B-aligned chunks first)
    float* dw            = ws;                                   // 262144 f
    unsigned short* ehi  = (unsigned short*)(dw + KC * DIM);     // 262144 us
    unsigned short* elo  = ehi + KC * DIM;                       // 262144 us
    float* e_sq          = (float*)(elo + KC * DIM);             // 1024 f
    int* idx             = (int*)(e_sq + KC);                    // 65536 i
    int* counts          = idx + BATCH;                          // 1024 i
    int* cursor          = counts + KC;                          // 1024 i
    int* sorted_rows     = cursor + KC;                          // 65536 i
    float* n_ws          = (float*)(sorted_rows + BATCH);        // 1 f

    prep_zero_kernel<<<dim3(KC), dim3(256), 0, stream>>>(
        emb, ehi, elo, e_sq, dw, counts, out);
    argmin_kernel<<<dim3(BATCH / 128), dim3(256), 0, stream>>>(
        z_e, ehi, elo, e_sq, idx, out + O_IDX, counts);
    prefix_stats_kernel<<<dim3(1), dim3(1024), 0, stream>>>(
        counts, cursor, ema_cs, out, n_ws);
    scatter_rows_kernel<<<dim3(BATCH / 256), dim3(256), 0, stream>>>(
        idx, cursor, sorted_rows);
    dw_zq_kernel<<<dim3(BATCH / SEG), dim3(256), 0, stream>>>(
        z_e, emb, idx, sorted_rows, out + O_ZQ, dw, out);
    finalize_emb<<<dim3(KC), dim3(256), 0, stream>>>(
        ema_w, dw, out + O_NCS, n_ws, out + O_EMB, out + O_NEW);
}

// Round 4
// 325.703 us; speedup vs baseline: 1.8121x; 1.8121x over previous
//
#include <hip/hip_runtime.h>
#include <hip/hip_bf16.h>
#include <math.h>

#define BATCH 65536
#define DIM 256
#define KC 1024
#define COMMIT 0.25f
#define DECAY 0.99f
#define EPSV 1e-5f

// Output layout (floats, concatenated in reference return order)
#define O_ZQ   0                       // 65536*256
#define O_LOSS 16777216                // 1
#define O_PERP 16777217                // 1
#define O_IDX  16777218                // 65536 (indices written as float values)
#define O_EMB  16842754                // 1024*256 new_embedding
#define O_NCS  17104898                // 1024 new_ema_cluster_size
#define O_NEW  17105922                // 1024*256 new_ema_w

typedef __attribute__((ext_vector_type(8))) short bf16x8;
typedef __attribute__((ext_vector_type(4))) float f32x4;

typedef __attribute__((address_space(1))) const void* as1_cvp;
typedef __attribute__((address_space(3))) void* as3_vp;

__device__ __forceinline__ void gload_lds16(const void* g, void* l) {
    // async 16B global->LDS (DMA path); LDS dest = wave-uniform base + lane*16
    __builtin_amdgcn_global_load_lds((as1_cvp)g, (as3_vp)l, 16, 0, 0);
}

__device__ __forceinline__ unsigned short bf16_rne(float x) {
    unsigned u = __builtin_bit_cast(unsigned, x);
    unsigned r = (u + 0x7FFFu + ((u >> 16) & 1u)) >> 16;
    return (unsigned short)r;
}
__device__ __forceinline__ float bf16_to_f(unsigned short h) {
    unsigned u = ((unsigned)h) << 16;
    return __builtin_bit_cast(float, u);
}

// ---------------- fused: zero accumulators + emb hi/lo split + e_sq ---------
// 1024 blocks x 256 thr. Block k: zeroes dw row k, prepares code row k
// (threads 0..63), zeroes counts[k] (thread 64), block 0 zeroes O_LOSS.
// Global layout per code row k (256 ushorts = 32 slots of 8): ORIGINAL slot s
// stored at slot (s ^ (k&7)).  Staging copies rows linearly into LDS via
// global_load_lds; the MFMA fragment read applies the same XOR -> identity,
// and the XOR spreads a wave's 16 rows across bank groups without padding.
__global__ __launch_bounds__(256) void prep_zero_kernel(
        const float* __restrict__ emb,
        unsigned short* __restrict__ ehi, unsigned short* __restrict__ elo,
        float* __restrict__ e_sq, float* __restrict__ dw,
        int* __restrict__ counts, float* __restrict__ out) {
    int k = blockIdx.x;
    int t = threadIdx.x;
    dw[(size_t)k * DIM + t] = 0.0f;
    if (t == 64) counts[k] = 0;
    if (k == 0 && t == 128) out[O_LOSS] = 0.0f;
    if (t < 64) {
        int lane = t;
        const float4* ep = (const float4*)(emb + (size_t)k * DIM);
        float4 e = ep[lane];
        float x[4] = {e.x, e.y, e.z, e.w};
        unsigned h[4], l[4];
        float s = 0.0f;
        #pragma unroll
        for (int j = 0; j < 4; ++j) {
            h[j] = bf16_rne(x[j]);
            l[j] = bf16_rne(x[j] - bf16_to_f((unsigned short)h[j]));
            s += x[j] * x[j];
        }
        uint2 ph = make_uint2(h[0] | (h[1] << 16), h[2] | (h[3] << 16));
        uint2 pl = make_uint2(l[0] | (l[1] << 16), l[2] | (l[3] << 16));
        int slot = lane >> 1;            // 16B slot (8 ushorts)
        int half = lane & 1;             // which 8B half of the slot
        int us = k * 256 + ((slot ^ (k & 7)) << 3) + (half << 2);
        *(uint2*)(ehi + us) = ph;
        *(uint2*)(elo + us) = pl;
        for (int off = 32; off; off >>= 1) s += __shfl_down(s, off, 64);
        if (lane == 0) e_sq[k] = s;
    }
}

// ---------------- MFMA distance + argmin (+fused histogram) -----------------
// CH_ROWS=16: 2x(8+8) KB double buffer + 4 KB esq = 36 KB LDS -> 4 blocks/CU
// by LDS.  __launch_bounds__(256,2) keeps the register allocator at 128 VGPR
// (the A-fragments alone need 128) -- (256,4) forced a 64-VGPR cap and
// spilled everything to scratch (FETCH 48->440 MB, dur 139->405 us, R3).
// HW residency = min(LDS=4, VGPR: 2048/128=16 waves/CU=4 blocks) = 4 blocks.
#define CH_ROWS 16
__global__ __launch_bounds__(256, 2) void argmin_kernel(
        const float* __restrict__ z_e,
        const unsigned short* __restrict__ ehi,
        const unsigned short* __restrict__ elo,
        const float* __restrict__ e_sq,
        int* __restrict__ idx_out, float* __restrict__ idx_f_out,
        int* __restrict__ counts) {
    __shared__ __align__(16) unsigned short bhi_s[2][CH_ROWS * 256]; // 2x8 KB
    __shared__ __align__(16) unsigned short blo_s[2][CH_ROWS * 256]; // 2x8 KB
    __shared__ float esq_s[KC];

    int tid = threadIdx.x;
    int w = tid >> 6;
    int lane = tid & 63;
    int m16 = lane & 15;
    int quad = lane >> 4;
    int base_m = blockIdx.x * 128 + w * 32;

#define STAGE(c, b) { \
    const char* gh_ = (const char*)ehi + (c) * 8192 + tid * 16; \
    const char* gl_ = (const char*)elo + (c) * 8192 + tid * 16; \
    char* lh_ = (char*)(bhi_s[b]) + tid * 16; \
    char* ll_ = (char*)(blo_s[b]) + tid * 16; \
    _Pragma("unroll") for (int r_ = 0; r_ < 2; ++r_) { \
        gload_lds16(gh_ + r_ * 4096, lh_ + r_ * 4096); \
        gload_lds16(gl_ + r_ * 4096, ll_ + r_ * 4096); } }

    // issue chunk-0 DMA first; A-fragment conversion below overlaps it
    STAGE(0, 0)

    #pragma unroll
    for (int i = 0; i < 4; ++i) esq_s[tid + i * 256] = e_sq[tid + i * 256];

    // load + split A fragments: A[m=lane&15][k=quad*8+j]
    bf16x8 ahi[2][8], alo[2][8];
    #pragma unroll
    for (int f = 0; f < 2; ++f) {
        const float* zr = z_e + (size_t)(base_m + f * 16 + m16) * DIM;
        #pragma unroll
        for (int ks = 0; ks < 8; ++ks) {
            const float4* p = (const float4*)(zr + ks * 32 + quad * 8);
            float4 x0 = p[0], x1 = p[1];
            float xs[8] = {x0.x, x0.y, x0.z, x0.w, x1.x, x1.y, x1.z, x1.w};
            #pragma unroll
            for (int j = 0; j < 8; ++j) {
                unsigned short h = bf16_rne(xs[j]);
                unsigned short l = bf16_rne(xs[j] - bf16_to_f(h));
                ahi[f][ks][j] = (short)h;
                alo[f][ks][j] = (short)l;
            }
        }
    }

    float best0[4] = {1e30f, 1e30f, 1e30f, 1e30f};
    float best1[4] = {1e30f, 1e30f, 1e30f, 1e30f};
    int bk0[4] = {0, 0, 0, 0};
    int bk1[4] = {0, 0, 0, 0};

    const int rsw = (m16 & 7) << 3;   // read-side XOR (in ushort units)

#define COMPUTE(c, b) { \
    f32x4 acc0 = {0.f, 0.f, 0.f, 0.f}; \
    f32x4 acc1 = {0.f, 0.f, 0.f, 0.f}; \
    const unsigned short* bh_row = bhi_s[b] + m16 * 256; \
    const unsigned short* bl_row = blo_s[b] + m16 * 256; \
    _Pragma("unroll") for (int ks_ = 0; ks_ < 8; ++ks_) { \
        int us_off = (((ks_ * 4 + quad) << 3) ^ rsw); \
        bf16x8 bh = *(const bf16x8*)(bh_row + us_off); \
        bf16x8 bl = *(const bf16x8*)(bl_row + us_off); \
        acc0 = __builtin_amdgcn_mfma_f32_16x16x32_bf16(ahi[0][ks_], bh, acc0, 0, 0, 0); \
        acc1 = __builtin_amdgcn_mfma_f32_16x16x32_bf16(ahi[1][ks_], bh, acc1, 0, 0, 0); \
        acc0 = __builtin_amdgcn_mfma_f32_16x16x32_bf16(ahi[0][ks_], bl, acc0, 0, 0, 0); \
        acc1 = __builtin_amdgcn_mfma_f32_16x16x32_bf16(ahi[1][ks_], bl, acc1, 0, 0, 0); \
        acc0 = __builtin_amdgcn_mfma_f32_16x16x32_bf16(alo[0][ks_], bh, acc0, 0, 0, 0); \
        acc1 = __builtin_amdgcn_mfma_f32_16x16x32_bf16(alo[1][ks_], bh, acc1, 0, 0, 0); } \
    int col = (c) * 16 + m16; \
    float es = esq_s[col]; \
    _Pragma("unroll") for (int r_ = 0; r_ < 4; ++r_) { \
        float d0 = es - 2.0f * acc0[r_]; \
        float d1 = es - 2.0f * acc1[r_]; \
        if (d0 < best0[r_]) { best0[r_] = d0; bk0[r_] = col; } \
        if (d1 < best1[r_]) { best1[r_] = d1; bk1[r_] = col; } } }

    __syncthreads();   // chunk-0 DMA + esq_s visible

    for (int c = 0; c < 64; c += 2) {
        STAGE(c + 1, 1)
        COMPUTE(c, 0)
        __syncthreads();           // drains STAGE(c+1); buf0 reads finished
        if (c + 2 < 64) STAGE(c + 2, 0)
        COMPUTE(c + 1, 1)
        __syncthreads();           // drains STAGE(c+2); buf1 reads finished
    }

    #pragma unroll
    for (int off = 1; off < 16; off <<= 1) {
        #pragma unroll
        for (int r = 0; r < 4; ++r) {
            float ov0 = __shfl_xor(best0[r], off, 64);
            int   ok0 = __shfl_xor(bk0[r], off, 64);
            if (ov0 < best0[r] || (ov0 == best0[r] && ok0 < bk0[r])) { best0[r] = ov0; bk0[r] = ok0; }
            float ov1 = __shfl_xor(best1[r], off, 64);
            int   ok1 = __shfl_xor(bk1[r], off, 64);
            if (ov1 < best1[r] || (ov1 == best1[r] && ok1 < bk1[r])) { best1[r] = ov1; bk1[r] = ok1; }
        }
    }
    if (m16 == 0) {
        #pragma unroll
        for (int r = 0; r < 4; ++r) {
            int row0 = base_m + quad * 4 + r;
            int row1 = base_m + 16 + quad * 4 + r;
            idx_out[row0] = bk0[r];
            idx_f_out[row0] = (float)bk0[r];
            idx_out[row1] = bk1[r];
            idx_f_out[row1] = (float)bk1[r];
            atomicAdd(&counts[bk0[r]], 1);   // fused histogram
            atomicAdd(&counts[bk1[r]], 1);
        }
    }
#undef STAGE
#undef COMPUTE
}

// ---------------- prefix scan + cluster stats (ncs, n, perplexity) ----------
__global__ __launch_bounds__(1024) void prefix_stats_kernel(
        const int* __restrict__ counts, int* __restrict__ cursor,
        const float* __restrict__ ema_cs, float* __restrict__ out,
        float* __restrict__ n_ws) {
    __shared__ int wsum[16];
    __shared__ float s1[1024];
    __shared__ float s2[1024];
    int t = threadIdx.x;
    int lane = t & 63;
    int wv = t >> 6;
    int c = counts[t];
    int x = c;
    #pragma unroll
    for (int off = 1; off < 64; off <<= 1) {
        int v = __shfl_up(x, off, 64);
        if (lane >= off) x += v;
    }
    if (lane == 63) wsum[wv] = x;
    // cluster stats while the scan syncs
    float cf = (float)c;
    float ncs = DECAY * ema_cs[t] + (1.0f - DECAY) * cf;
    out[O_NCS + t] = ncs;
    float p = cf / (float)BATCH;
    s1[t] = ncs;
    s2[t] = p * logf(p + 1e-10f);
    __syncthreads();
    if (wv == 0) {
        int v = (lane < 16) ? wsum[lane] : 0;
        #pragma unroll
        for (int off = 1; off < 16; off <<= 1) {
            int u = __shfl_up(v, off, 64);
            if (lane >= off) v += u;
        }
        if (lane < 16) wsum[lane] = v;
    }
    __syncthreads();
    int woff = (wv == 0) ? 0 : wsum[wv - 1];
    cursor[t] = woff + x - c;   // exclusive
    for (int s = 512; s; s >>= 1) {
        if (t < s) { s1[t] += s1[t + s]; s2[t] += s2[t + s]; }
        __syncthreads();
    }
    if (t == 0) {
        n_ws[0] = s1[0];
        out[O_PERP] = expf(-s2[0]);
    }
}

// ---------------- bucket rows by cluster ------------------------------------
__global__ __launch_bounds__(256) void scatter_rows_kernel(
        const int* __restrict__ idx, int* __restrict__ cursor,
        int* __restrict__ sorted_rows) {
    int i = blockIdx.x * 256 + threadIdx.x;
    int k = idx[i];
    int pos = atomicAdd(&cursor[k], 1);
    sorted_rows[pos] = i;
}

// ---------------- fused: z_q gather + loss + dw ------------------------------
// 4 waves/block; wave w owns rows [w*16, w*16+16) of the block's 64-row
// segment; lane owns a float4 column slice (16 B/lane coalescing).  Loads
// batched 8-deep; per-key running float4 acc flushed via atomics on change.
// Loss partial is pre-scaled and atomically added straight to out[O_LOSS].
#define SEG 64
__global__ __launch_bounds__(256) void dw_zq_kernel(
        const float* __restrict__ z_e, const float* __restrict__ emb,
        const int* __restrict__ idx, const int* __restrict__ sorted_rows,
        float* __restrict__ zq_out, float* __restrict__ dw,
        float* __restrict__ out) {
    __shared__ int rows_s[SEG];
    __shared__ int keys_s[SEG];
    int t = threadIdx.x;
    int w = t >> 6;
    int lane = t & 63;
    int base = blockIdx.x * SEG;
    if (t < SEG) {
        int r = sorted_rows[base + t];
        rows_s[t] = r;
        keys_s[t] = idx[r];
    }
    __syncthreads();

    int c4 = lane * 4;
    float4 acc = make_float4(0.f, 0.f, 0.f, 0.f);
    float lsum = 0.0f;
    int kprev = keys_s[w * 16];
    #pragma unroll
    for (int g = 0; g < 2; ++g) {
        int rowb[8], kb[8];
        float4 zb[8], qb[8];
        #pragma unroll
        for (int u = 0; u < 8; ++u) {
            int i = w * 16 + g * 8 + u;
            rowb[u] = rows_s[i];
            kb[u] = keys_s[i];
        }
        #pragma unroll
        for (int u = 0; u < 8; ++u) {
            zb[u] = *(const float4*)(z_e + (size_t)rowb[u] * DIM + c4);
            qb[u] = *(const float4*)(emb + (size_t)kb[u] * DIM + c4);
        }
        #pragma unroll
        for (int u = 0; u < 8; ++u) {
            float4 z = zb[u], q = qb[u];
            float4 d = make_float4(q.x - z.x, q.y - z.y, q.z - z.z, q.w - z.w);
            float4 o = make_float4(z.x + d.x, z.y + d.y, z.z + d.z, z.w + d.w);
            *(float4*)(zq_out + (size_t)rowb[u] * DIM + c4) = o;
            lsum += d.x * d.x + d.y * d.y + d.z * d.z + d.w * d.w;
            if (kb[u] != kprev) {
                float* dst = dw + (size_t)kprev * DIM + c4;
                atomicAdd(dst + 0, acc.x);
                atomicAdd(dst + 1, acc.y);
                atomicAdd(dst + 2, acc.z);
                atomicAdd(dst + 3, acc.w);
                acc = make_float4(0.f, 0.f, 0.f, 0.f);
                kprev = kb[u];
            }
            acc.x += z.x; acc.y += z.y; acc.z += z.z; acc.w += z.w;
        }
    }
    {
        float* dst = dw + (size_t)kprev * DIM + c4;
        atomicAdd(dst + 0, acc.x);
        atomicAdd(dst + 1, acc.y);
        atomicAdd(dst + 2, acc.z);
        atomicAdd(dst + 3, acc.w);
    }

    __shared__ float red[256];
    red[t] = lsum;
    __syncthreads();
    for (int s = 128; s; s >>= 1) {
        if (t < s) red[t] += red[t + s];
        __syncthreads();
    }
    if (t == 0)
        atomicAdd(out + O_LOSS, red[0] * (COMMIT / ((float)BATCH * (float)DIM)));
}

// ---------------- new_ema_w and new_embedding -------------------------------
__global__ __launch_bounds__(256) void finalize_emb(
        const float* __restrict__ ema_w, const float* __restrict__ dw,
        const float* __restrict__ ncs_arr, const float* __restrict__ n_ws,
        float* __restrict__ out_emb, float* __restrict__ out_emaw) {
    int k = blockIdx.x;
    int d = threadIdx.x;
    size_t i = (size_t)k * DIM + d;
    float w = DECAY * ema_w[i] + (1.0f - DECAY) * dw[i];
    out_emaw[i] = w;
    float n = n_ws[0];
    float ncs = ncs_arr[k];
    float smoothed = (ncs + EPSV) / (n + (float)KC * EPSV) * n;
    out_emb[i] = w / smoothed;
}

extern "C" void kernel_launch(void* const* d_in, const int* in_sizes, int n_in,
                              void* d_out, int out_size, void* d_ws, size_t ws_size,
                              hipStream_t stream) {
    const float* z_e    = (const float*)d_in[0];
    const float* emb    = (const float*)d_in[1];
    const float* ema_cs = (const float*)d_in[2];
    const float* ema_w  = (const float*)d_in[3];
    float* out = (float*)d_out;
    float* ws = (float*)d_ws;

    // workspace layout (16B-aligned chunks first)
    float* dw            = ws;                                   // 262144 f
    unsigned short* ehi  = (unsigned short*)(dw + KC * DIM);     // 262144 us
    unsigned short* elo  = ehi + KC * DIM;                       // 262144 us
    float* e_sq          = (float*)(elo + KC * DIM);             // 1024 f
    int* idx             = (int*)(e_sq + KC);                    // 65536 i
    int* counts          = idx + BATCH;                          // 1024 i
    int* cursor          = counts + KC;                          // 1024 i
    int* sorted_rows     = cursor + KC;                          // 65536 i
    float* n_ws          = (float*)(sorted_rows + BATCH);        // 1 f

    prep_zero_kernel<<<dim3(KC), dim3(256), 0, stream>>>(
        emb, ehi, elo, e_sq, dw, counts, out);
    argmin_kernel<<<dim3(BATCH / 128), dim3(256), 0, stream>>>(
        z_e, ehi, elo, e_sq, idx, out + O_IDX, counts);
    prefix_stats_kernel<<<dim3(1), dim3(1024), 0, stream>>>(
        counts, cursor, ema_cs, out, n_ws);
    scatter_rows_kernel<<<dim3(BATCH / 256), dim3(256), 0, stream>>>(
        idx, cursor, sorted_rows);
    dw_zq_kernel<<<dim3(BATCH / SEG), dim3(256), 0, stream>>>(
        z_e, emb, idx, sorted_rows, out + O_ZQ, dw, out);
    finalize_emb<<<dim3(KC), dim3(256), 0, stream>>>(
        ema_w, dw, out + O_NCS, n_ws, out + O_EMB, out + O_NEW);
}

// Round 5
// 308.319 us; speedup vs baseline: 1.9143x; 1.0564x over previous
//
#include <hip/hip_runtime.h>
#include <hip/hip_bf16.h>
#include <math.h>

#define BATCH 65536
#define DIM 256
#define KC 1024
#define COMMIT 0.25f
#define DECAY 0.99f
#define EPSV 1e-5f

// Output layout (floats, concatenated in reference return order)
#define O_ZQ   0                       // 65536*256
#define O_LOSS 16777216                // 1
#define O_PERP 16777217                // 1
#define O_IDX  16777218                // 65536 (indices written as float values)
#define O_EMB  16842754                // 1024*256 new_embedding
#define O_NCS  17104898                // 1024 new_ema_cluster_size
#define O_NEW  17105922                // 1024*256 new_ema_w

typedef __attribute__((ext_vector_type(8))) short bf16x8;
typedef __attribute__((ext_vector_type(4))) float f32x4;

typedef __attribute__((address_space(1))) const void* as1_cvp;
typedef __attribute__((address_space(3))) void* as3_vp;

__device__ __forceinline__ void gload_lds16(const void* g, void* l) {
    // async 16B global->LDS (DMA path); LDS dest = wave-uniform base + lane*16
    __builtin_amdgcn_global_load_lds((as1_cvp)g, (as3_vp)l, 16, 0, 0);
}

__device__ __forceinline__ unsigned short bf16_rne(float x) {
    unsigned u = __builtin_bit_cast(unsigned, x);
    unsigned r = (u + 0x7FFFu + ((u >> 16) & 1u)) >> 16;
    return (unsigned short)r;
}
__device__ __forceinline__ float bf16_to_f(unsigned short h) {
    unsigned u = ((unsigned)h) << 16;
    return __builtin_bit_cast(float, u);
}
// monotone float->u32 map: a<b  <=>  enc(a)<enc(b)
__device__ __forceinline__ unsigned enc_f32(float f) {
    unsigned u = __builtin_bit_cast(unsigned, f);
    return u ^ ((unsigned)((int)u >> 31) | 0x80000000u);
}

// ---------------- fused: zero accumulators + emb hi/lo split + e_sq ---------
// 1024 blocks x 256 thr. Block k: zeroes dw row k, prepares code row k
// (threads 0..63), zeroes counts[k] (thread 64), block 0 zeroes O_LOSS.
// Global layout per code row k (256 ushorts = 32 slots of 8): ORIGINAL slot s
// stored at slot (s ^ (k&7)).  Staging copies rows linearly into LDS via
// global_load_lds; the MFMA fragment read applies the same XOR -> identity,
// and the XOR spreads a wave's 16 rows across bank groups without padding.
__global__ __launch_bounds__(256) void prep_zero_kernel(
        const float* __restrict__ emb,
        unsigned short* __restrict__ ehi, unsigned short* __restrict__ elo,
        float* __restrict__ e_sq, float* __restrict__ dw,
        int* __restrict__ counts, float* __restrict__ out) {
    int k = blockIdx.x;
    int t = threadIdx.x;
    dw[(size_t)k * DIM + t] = 0.0f;
    if (t == 64) counts[k] = 0;
    if (k == 0 && t == 128) out[O_LOSS] = 0.0f;
    if (t < 64) {
        int lane = t;
        const float4* ep = (const float4*)(emb + (size_t)k * DIM);
        float4 e = ep[lane];
        float x[4] = {e.x, e.y, e.z, e.w};
        unsigned h[4], l[4];
        float s = 0.0f;
        #pragma unroll
        for (int j = 0; j < 4; ++j) {
            h[j] = bf16_rne(x[j]);
            l[j] = bf16_rne(x[j] - bf16_to_f((unsigned short)h[j]));
            s += x[j] * x[j];
        }
        uint2 ph = make_uint2(h[0] | (h[1] << 16), h[2] | (h[3] << 16));
        uint2 pl = make_uint2(l[0] | (l[1] << 16), l[2] | (l[3] << 16));
        int slot = lane >> 1;            // 16B slot (8 ushorts)
        int half = lane & 1;             // which 8B half of the slot
        int us = k * 256 + ((slot ^ (k & 7)) << 3) + (half << 2);
        *(uint2*)(ehi + us) = ph;
        *(uint2*)(elo + us) = pl;
        for (int off = 32; off; off >>= 1) s += __shfl_down(s, off, 64);
        if (lane == 0) e_sq[k] = s;
    }
}

// ---------------- MFMA distance + argmin over HALF the codebook -------------
// Grid 1024: block = (row-group bm = blockIdx>>1) x (half = blockIdx&1).
// Each block scans 512 codes (32 chunks of 16).  LDS = 2x(8+8) KB dbuf +
// 2 KB esq = 34 KB -> 4 blocks/CU; VGPR 128 -> 4 waves/SIMD.  This fixes the
// R4 failure: grid 512 gave only 2 blocks/CU regardless of LDS (grid-limited).
// Per-row result written as u64 key (orderable-dist<<32 | col); tiny combine
// kernel merges the two halves.  Per-CU LDS/staging traffic unchanged.
#define CH_ROWS 16
__global__ __launch_bounds__(256, 2) void argmin_kernel(
        const float* __restrict__ z_e,
        const unsigned short* __restrict__ ehi,
        const unsigned short* __restrict__ elo,
        const float* __restrict__ e_sq,
        unsigned long long* __restrict__ part) {
    __shared__ __align__(16) unsigned short bhi_s[2][CH_ROWS * 256]; // 2x8 KB
    __shared__ __align__(16) unsigned short blo_s[2][CH_ROWS * 256]; // 2x8 KB
    __shared__ float esq_s[512];

    int tid = threadIdx.x;
    int w = tid >> 6;
    int lane = tid & 63;
    int m16 = lane & 15;
    int quad = lane >> 4;
    int half = blockIdx.x & 1;
    int base_m = (blockIdx.x >> 1) * 128 + w * 32;
    const char* ehi_b = (const char*)ehi + half * 262144;   // 512 rows * 512 B
    const char* elo_b = (const char*)elo + half * 262144;

#define STAGE(c, b) { \
    const char* gh_ = ehi_b + (c) * 8192 + tid * 16; \
    const char* gl_ = elo_b + (c) * 8192 + tid * 16; \
    char* lh_ = (char*)(bhi_s[b]) + tid * 16; \
    char* ll_ = (char*)(blo_s[b]) + tid * 16; \
    _Pragma("unroll") for (int r_ = 0; r_ < 2; ++r_) { \
        gload_lds16(gh_ + r_ * 4096, lh_ + r_ * 4096); \
        gload_lds16(gl_ + r_ * 4096, ll_ + r_ * 4096); } }

    // issue chunk-0 DMA first; A-fragment conversion below overlaps it
    STAGE(0, 0)

    esq_s[tid] = e_sq[(half << 9) + tid];
    esq_s[tid + 256] = e_sq[(half << 9) + tid + 256];

    // load + split A fragments: A[m=lane&15][k=quad*8+j]
    bf16x8 ahi[2][8], alo[2][8];
    #pragma unroll
    for (int f = 0; f < 2; ++f) {
        const float* zr = z_e + (size_t)(base_m + f * 16 + m16) * DIM;
        #pragma unroll
        for (int ks = 0; ks < 8; ++ks) {
            const float4* p = (const float4*)(zr + ks * 32 + quad * 8);
            float4 x0 = p[0], x1 = p[1];
            float xs[8] = {x0.x, x0.y, x0.z, x0.w, x1.x, x1.y, x1.z, x1.w};
            #pragma unroll
            for (int j = 0; j < 8; ++j) {
                unsigned short h = bf16_rne(xs[j]);
                unsigned short l = bf16_rne(xs[j] - bf16_to_f(h));
                ahi[f][ks][j] = (short)h;
                alo[f][ks][j] = (short)l;
            }
        }
    }

    float best0[4] = {1e30f, 1e30f, 1e30f, 1e30f};
    float best1[4] = {1e30f, 1e30f, 1e30f, 1e30f};
    int bk0[4] = {0, 0, 0, 0};
    int bk1[4] = {0, 0, 0, 0};

    const int rsw = (m16 & 7) << 3;   // read-side XOR (in ushort units)

#define COMPUTE(c, b) { \
    f32x4 acc0 = {0.f, 0.f, 0.f, 0.f}; \
    f32x4 acc1 = {0.f, 0.f, 0.f, 0.f}; \
    const unsigned short* bh_row = bhi_s[b] + m16 * 256; \
    const unsigned short* bl_row = blo_s[b] + m16 * 256; \
    _Pragma("unroll") for (int ks_ = 0; ks_ < 8; ++ks_) { \
        int us_off = (((ks_ * 4 + quad) << 3) ^ rsw); \
        bf16x8 bh = *(const bf16x8*)(bh_row + us_off); \
        bf16x8 bl = *(const bf16x8*)(bl_row + us_off); \
        acc0 = __builtin_amdgcn_mfma_f32_16x16x32_bf16(ahi[0][ks_], bh, acc0, 0, 0, 0); \
        acc1 = __builtin_amdgcn_mfma_f32_16x16x32_bf16(ahi[1][ks_], bh, acc1, 0, 0, 0); \
        acc0 = __builtin_amdgcn_mfma_f32_16x16x32_bf16(ahi[0][ks_], bl, acc0, 0, 0, 0); \
        acc1 = __builtin_amdgcn_mfma_f32_16x16x32_bf16(ahi[1][ks_], bl, acc1, 0, 0, 0); \
        acc0 = __builtin_amdgcn_mfma_f32_16x16x32_bf16(alo[0][ks_], bh, acc0, 0, 0, 0); \
        acc1 = __builtin_amdgcn_mfma_f32_16x16x32_bf16(alo[1][ks_], bh, acc1, 0, 0, 0); } \
    int lcol = (c) * 16 + m16; \
    int col = (half << 9) + lcol; \
    float es = esq_s[lcol]; \
    _Pragma("unroll") for (int r_ = 0; r_ < 4; ++r_) { \
        float d0 = es - 2.0f * acc0[r_]; \
        float d1 = es - 2.0f * acc1[r_]; \
        if (d0 < best0[r_]) { best0[r_] = d0; bk0[r_] = col; } \
        if (d1 < best1[r_]) { best1[r_] = d1; bk1[r_] = col; } } }

    __syncthreads();   // chunk-0 DMA + esq_s visible

    for (int c = 0; c < 32; c += 2) {
        STAGE(c + 1, 1)
        COMPUTE(c, 0)
        __syncthreads();           // drains STAGE(c+1); buf0 reads finished
        if (c + 2 < 32) STAGE(c + 2, 0)
        COMPUTE(c + 1, 1)
        __syncthreads();           // drains STAGE(c+2); buf1 reads finished
    }

    #pragma unroll
    for (int off = 1; off < 16; off <<= 1) {
        #pragma unroll
        for (int r = 0; r < 4; ++r) {
            float ov0 = __shfl_xor(best0[r], off, 64);
            int   ok0 = __shfl_xor(bk0[r], off, 64);
            if (ov0 < best0[r] || (ov0 == best0[r] && ok0 < bk0[r])) { best0[r] = ov0; bk0[r] = ok0; }
            float ov1 = __shfl_xor(best1[r], off, 64);
            int   ok1 = __shfl_xor(bk1[r], off, 64);
            if (ov1 < best1[r] || (ov1 == best1[r] && ok1 < bk1[r])) { best1[r] = ov1; bk1[r] = ok1; }
        }
    }
    if (m16 == 0) {
        #pragma unroll
        for (int r = 0; r < 4; ++r) {
            int row0 = base_m + quad * 4 + r;
            int row1 = base_m + 16 + quad * 4 + r;
            unsigned long long k0 =
                ((unsigned long long)enc_f32(best0[r]) << 32) | (unsigned)bk0[r];
            unsigned long long k1 =
                ((unsigned long long)enc_f32(best1[r]) << 32) | (unsigned)bk1[r];
            part[row0 * 2 + half] = k0;
            part[row1 * 2 + half] = k1;
        }
    }
#undef STAGE
#undef COMPUTE
}

// ---------------- merge halves + idx outputs + histogram --------------------
// 128 blocks x 256 thr; block handles 512 rows.  min(u64 key) picks smaller
// dist, then smaller col on tie (cols disjoint across halves).
__global__ __launch_bounds__(256) void combine_kernel(
        const unsigned long long* __restrict__ part,
        int* __restrict__ idx_out, float* __restrict__ idx_f_out,
        int* __restrict__ counts) {
    __shared__ int h[KC];
    int t = threadIdx.x;
    #pragma unroll
    for (int i = t; i < KC; i += 256) h[i] = 0;
    __syncthreads();
    int base = blockIdx.x * 512;
    #pragma unroll
    for (int j = 0; j < 2; ++j) {
        int row = base + j * 256 + t;
        unsigned long long k0 = part[row * 2];
        unsigned long long k1 = part[row * 2 + 1];
        unsigned long long m = k0 < k1 ? k0 : k1;
        int k = (int)(m & 0xFFFFFFFFu);
        idx_out[row] = k;
        idx_f_out[row] = (float)k;
        atomicAdd(&h[k], 1);
    }
    __syncthreads();
    #pragma unroll
    for (int i = t; i < KC; i += 256) if (h[i]) atomicAdd(&counts[i], h[i]);
}

// ---------------- prefix scan + cluster stats (ncs, n, perplexity) ----------
__global__ __launch_bounds__(1024) void prefix_stats_kernel(
        const int* __restrict__ counts, int* __restrict__ cursor,
        const float* __restrict__ ema_cs, float* __restrict__ out,
        float* __restrict__ n_ws) {
    __shared__ int wsum[16];
    __shared__ float s1[1024];
    __shared__ float s2[1024];
    int t = threadIdx.x;
    int lane = t & 63;
    int wv = t >> 6;
    int c = counts[t];
    int x = c;
    #pragma unroll
    for (int off = 1; off < 64; off <<= 1) {
        int v = __shfl_up(x, off, 64);
        if (lane >= off) x += v;
    }
    if (lane == 63) wsum[wv] = x;
    // cluster stats while the scan syncs
    float cf = (float)c;
    float ncs = DECAY * ema_cs[t] + (1.0f - DECAY) * cf;
    out[O_NCS + t] = ncs;
    float p = cf / (float)BATCH;
    s1[t] = ncs;
    s2[t] = p * logf(p + 1e-10f);
    __syncthreads();
    if (wv == 0) {
        int v = (lane < 16) ? wsum[lane] : 0;
        #pragma unroll
        for (int off = 1; off < 16; off <<= 1) {
            int u = __shfl_up(v, off, 64);
            if (lane >= off) v += u;
        }
        if (lane < 16) wsum[lane] = v;
    }
    __syncthreads();
    int woff = (wv == 0) ? 0 : wsum[wv - 1];
    cursor[t] = woff + x - c;   // exclusive
    for (int s = 512; s; s >>= 1) {
        if (t < s) { s1[t] += s1[t + s]; s2[t] += s2[t + s]; }
        __syncthreads();
    }
    if (t == 0) {
        n_ws[0] = s1[0];
        out[O_PERP] = expf(-s2[0]);
    }
}

// ---------------- bucket rows by cluster ------------------------------------
__global__ __launch_bounds__(256) void scatter_rows_kernel(
        const int* __restrict__ idx, int* __restrict__ cursor,
        int* __restrict__ sorted_rows) {
    int i = blockIdx.x * 256 + threadIdx.x;
    int k = idx[i];
    int pos = atomicAdd(&cursor[k], 1);
    sorted_rows[pos] = i;
}

// ---------------- fused: z_q gather + loss + dw ------------------------------
// 4 waves/block; wave w owns rows [w*16, w*16+16) of the block's 64-row
// segment; lane owns a float4 column slice (16 B/lane coalescing).  Loads
// batched 8-deep; per-key running float4 acc flushed via atomics on change.
// Loss partial is pre-scaled and atomically added straight to out[O_LOSS].
#define SEG 64
__global__ __launch_bounds__(256) void dw_zq_kernel(
        const float* __restrict__ z_e, const float* __restrict__ emb,
        const int* __restrict__ idx, const int* __restrict__ sorted_rows,
        float* __restrict__ zq_out, float* __restrict__ dw,
        float* __restrict__ out) {
    __shared__ int rows_s[SEG];
    __shared__ int keys_s[SEG];
    int t = threadIdx.x;
    int w = t >> 6;
    int lane = t & 63;
    int base = blockIdx.x * SEG;
    if (t < SEG) {
        int r = sorted_rows[base + t];
        rows_s[t] = r;
        keys_s[t] = idx[r];
    }
    __syncthreads();

    int c4 = lane * 4;
    float4 acc = make_float4(0.f, 0.f, 0.f, 0.f);
    float lsum = 0.0f;
    int kprev = keys_s[w * 16];
    #pragma unroll
    for (int g = 0; g < 2; ++g) {
        int rowb[8], kb[8];
        float4 zb[8], qb[8];
        #pragma unroll
        for (int u = 0; u < 8; ++u) {
            int i = w * 16 + g * 8 + u;
            rowb[u] = rows_s[i];
            kb[u] = keys_s[i];
        }
        #pragma unroll
        for (int u = 0; u < 8; ++u) {
            zb[u] = *(const float4*)(z_e + (size_t)rowb[u] * DIM + c4);
            qb[u] = *(const float4*)(emb + (size_t)kb[u] * DIM + c4);
        }
        #pragma unroll
        for (int u = 0; u < 8; ++u) {
            float4 z = zb[u], q = qb[u];
            float4 d = make_float4(q.x - z.x, q.y - z.y, q.z - z.z, q.w - z.w);
            float4 o = make_float4(z.x + d.x, z.y + d.y, z.z + d.z, z.w + d.w);
            *(float4*)(zq_out + (size_t)rowb[u] * DIM + c4) = o;
            lsum += d.x * d.x + d.y * d.y + d.z * d.z + d.w * d.w;
            if (kb[u] != kprev) {
                float* dst = dw + (size_t)kprev * DIM + c4;
                atomicAdd(dst + 0, acc.x);
                atomicAdd(dst + 1, acc.y);
                atomicAdd(dst + 2, acc.z);
                atomicAdd(dst + 3, acc.w);
                acc = make_float4(0.f, 0.f, 0.f, 0.f);
                kprev = kb[u];
            }
            acc.x += z.x; acc.y += z.y; acc.z += z.z; acc.w += z.w;
        }
    }
    {
        float* dst = dw + (size_t)kprev * DIM + c4;
        atomicAdd(dst + 0, acc.x);
        atomicAdd(dst + 1, acc.y);
        atomicAdd(dst + 2, acc.z);
        atomicAdd(dst + 3, acc.w);
    }

    __shared__ float red[256];
    red[t] = lsum;
    __syncthreads();
    for (int s = 128; s; s >>= 1) {
        if (t < s) red[t] += red[t + s];
        __syncthreads();
    }
    if (t == 0)
        atomicAdd(out + O_LOSS, red[0] * (COMMIT / ((float)BATCH * (float)DIM)));
}

// ---------------- new_ema_w and new_embedding -------------------------------
__global__ __launch_bounds__(256) void finalize_emb(
        const float* __restrict__ ema_w, const float* __restrict__ dw,
        const float* __restrict__ ncs_arr, const float* __restrict__ n_ws,
        float* __restrict__ out_emb, float* __restrict__ out_emaw) {
    int k = blockIdx.x;
    int d = threadIdx.x;
    size_t i = (size_t)k * DIM + d;
    float w = DECAY * ema_w[i] + (1.0f - DECAY) * dw[i];
    out_emaw[i] = w;
    float n = n_ws[0];
    float ncs = ncs_arr[k];
    float smoothed = (ncs + EPSV) / (n + (float)KC * EPSV) * n;
    out_emb[i] = w / smoothed;
}

extern "C" void kernel_launch(void* const* d_in, const int* in_sizes, int n_in,
                              void* d_out, int out_size, void* d_ws, size_t ws_size,
                              hipStream_t stream) {
    const float* z_e    = (const float*)d_in[0];
    const float* emb    = (const float*)d_in[1];
    const float* ema_cs = (const float*)d_in[2];
    const float* ema_w  = (const float*)d_in[3];
    float* out = (float*)d_out;
    float* ws = (float*)d_ws;

    // workspace layout (16B-aligned chunks first)
    float* dw            = ws;                                   // 262144 f
    unsigned short* ehi  = (unsigned short*)(dw + KC * DIM);     // 262144 us
    unsigned short* elo  = ehi + KC * DIM;                       // 262144 us
    unsigned long long* part = (unsigned long long*)(elo + KC * DIM); // 131072 u64
    float* e_sq          = (float*)(part + 2 * BATCH);           // 1024 f
    int* idx             = (int*)(e_sq + KC);                    // 65536 i
    int* counts          = idx + BATCH;                          // 1024 i
    int* cursor          = counts + KC;                          // 1024 i
    int* sorted_rows     = cursor + KC;                          // 65536 i
    float* n_ws          = (float*)(sorted_rows + BATCH);        // 1 f

    prep_zero_kernel<<<dim3(KC), dim3(256), 0, stream>>>(
        emb, ehi, elo, e_sq, dw, counts, out);
    argmin_kernel<<<dim3(BATCH / 128 * 2), dim3(256), 0, stream>>>(
        z_e, ehi, elo, e_sq, part);
    combine_kernel<<<dim3(BATCH / 512), dim3(256), 0, stream>>>(
        part, idx, out + O_IDX, counts);
    prefix_stats_kernel<<<dim3(1), dim3(1024), 0, stream>>>(
        counts, cursor, ema_cs, out, n_ws);
    scatter_rows_kernel<<<dim3(BATCH / 256), dim3(256), 0, stream>>>(
        idx, cursor, sorted_rows);
    dw_zq_kernel<<<dim3(BATCH / SEG), dim3(256), 0, stream>>>(
        z_e, emb, idx, sorted_rows, out + O_ZQ, dw, out);
    finalize_emb<<<dim3(KC), dim3(256), 0, stream>>>(
        ema_w, dw, out + O_NCS, n_ws, out + O_EMB, out + O_NEW);
}